// Round 4
// baseline (306.345 us; speedup 1.0000x reference)
//
#include <hip/hip_runtime.h>

// SAM ViT-B global attention, MI355X bf16-MFMA implementation.
// R3 (resubmit; R3 bench was lost to GPU acquisition timeout):
// flash rebuilt on 32x32x16 MFMA, key-split waves (wave = qhalf x keyhalf),
// end-merge of per-wave partials; halved LDS traffic + MFMA count;
// register-resident addresses. Other kernels unchanged from R2.

typedef __bf16 bf16;
typedef __bf16 bf16x8 __attribute__((ext_vector_type(8)));
typedef __bf16 bf16x4 __attribute__((ext_vector_type(4)));
typedef float f32x4 __attribute__((ext_vector_type(4)));
typedef float f32x16 __attribute__((ext_vector_type(16)));
typedef unsigned int u32;

__device__ __forceinline__ f32x4 mfma16(bf16x8 a, bf16x8 b, f32x4 c) {
  return __builtin_amdgcn_mfma_f32_16x16x32_bf16(a, b, c, 0, 0, 0);
}
__device__ __forceinline__ f32x16 mfma32(bf16x8 a, bf16x8 b, f32x16 c) {
  return __builtin_amdgcn_mfma_f32_32x32x16_bf16(a, b, c, 0, 0, 0);
}

typedef const __attribute__((address_space(1))) void* gas_ptr;
typedef __attribute__((address_space(3))) void* las_ptr;
__device__ __forceinline__ void gl_lds16(const void* g, void* l) {
  __builtin_amdgcn_global_load_lds((gas_ptr)g, (las_ptr)l, 16, 0, 0);
}

#define L2E 1.4426950408889634f

// ---------------- fp32 -> bf16 convert, 3 tensors in one launch ----------------
__global__ __launch_bounds__(256) void cvt3(
    const float* __restrict__ a, bf16* __restrict__ oa,
    const float* __restrict__ b, bf16* __restrict__ ob,
    const float* __restrict__ c, bf16* __restrict__ oc) {
  int blk = blockIdx.x;
  const float* src;
  bf16* dst;
  int base;
  if (blk < 1536)       { src = a; dst = oa; base = blk; }
  else if (blk < 2400)  { src = b; dst = ob; base = blk - 1536; }
  else                  { src = c; dst = oc; base = blk - 2400; }
  int idx = (base * 256 + threadIdx.x) * 8;
  f32x4 x = *(const f32x4*)&src[idx];
  f32x4 y = *(const f32x4*)&src[idx + 4];
  bf16x8 o;
#pragma unroll
  for (int j = 0; j < 4; j++) { o[j] = (bf16)x[j]; o[j + 4] = (bf16)y[j]; }
  *(bf16x8*)&dst[idx] = o;
}

// ---------------- 128x128 GEMM, C = A @ B^T + bias ----------------
template <int MODE>
__global__ __launch_bounds__(256) void gemm128(
    const bf16* __restrict__ A, const bf16* __restrict__ B,
    const float* __restrict__ bias, int K, int N,
    bf16* __restrict__ q_s, bf16* __restrict__ k_s, bf16* __restrict__ v_t,
    float* __restrict__ outf) {
  __shared__ __align__(16) bf16 lA[128 * 32];
  __shared__ __align__(16) bf16 lB[128 * 32];
  const int tid = threadIdx.x;
  const int w = tid >> 6, l = tid & 63;
  const int n0 = blockIdx.x * 128, m0 = blockIdx.y * 128;

  f32x4 acc[4][4] = {};

  const int ch0 = w * 2, ch1 = ch0 + 1;
  const int r0 = ch0 * 16 + (l >> 2), r1 = ch1 * 16 + (l >> 2);
  const int ce = (l & 3) * 8;
  const int mw = (w & 1) * 64, nw = (w >> 1) * 64;

  for (int k0 = 0; k0 < K; k0 += 32) {
    __syncthreads();
    gl_lds16(&A[(size_t)(m0 + r0) * K + k0 + ce], &lA[ch0 * 512]);
    gl_lds16(&A[(size_t)(m0 + r1) * K + k0 + ce], &lA[ch1 * 512]);
    gl_lds16(&B[(size_t)(n0 + r0) * K + k0 + ce], &lB[ch0 * 512]);
    gl_lds16(&B[(size_t)(n0 + r1) * K + k0 + ce], &lB[ch1 * 512]);
    __syncthreads();
    bf16x8 af[4], bfr[4];
#pragma unroll
    for (int i = 0; i < 4; i++)
      af[i] = *(const bf16x8*)&lA[(mw + i * 16 + (l & 15)) * 32 + (l >> 4) * 8];
#pragma unroll
    for (int i = 0; i < 4; i++)
      bfr[i] = *(const bf16x8*)&lB[(nw + i * 16 + (l & 15)) * 32 + (l >> 4) * 8];
#pragma unroll
    for (int mi = 0; mi < 4; mi++)
#pragma unroll
      for (int ni = 0; ni < 4; ni++)
        acc[mi][ni] = mfma16(af[mi], bfr[ni], acc[mi][ni]);
  }

#pragma unroll
  for (int ni = 0; ni < 4; ni++) {
    const int n = n0 + nw + ni * 16 + (l & 15);
    const float bv = bias[n];
#pragma unroll
    for (int mi = 0; mi < 4; mi++) {
#pragma unroll
      for (int i = 0; i < 4; i++) {
        const int m = m0 + mw + mi * 16 + (l >> 4) * 4 + i;
        const float v = acc[mi][ni][i] + bv;
        if (MODE == 0) {
          const int which = n / 768, hn = n % 768;
          const int head = hn >> 6, hd = hn & 63;
          if (which == 0)      q_s[((size_t)head * 4096 + m) * 64 + hd] = (bf16)v;
          else if (which == 1) k_s[((size_t)head * 4096 + m) * 64 + hd] = (bf16)v;
          else                 v_t[((size_t)head * 64 + hd) * 4096 + m] = (bf16)v;
        } else {
          outf[(size_t)m * N + n] = v;
        }
      }
    }
  }
}

// ---------------- rel_w bias kernel ----------------
__global__ __launch_bounds__(64) void rel_pos_w(
    const bf16* __restrict__ q_s, const float* __restrict__ table,
    float* __restrict__ out) {
  const int l = threadIdx.x;
  const int p = blockIdx.x, head = blockIdx.y;
  const size_t hbase = (size_t)head * 4096 * 64;

  f32x4 acc[4][4] = {};
#pragma unroll
  for (int ks = 0; ks < 2; ks++) {
    bf16x8 af[4], bfr[4];
#pragma unroll
    for (int mi = 0; mi < 4; mi++) {
      const int row = mi * 16 + (l & 15);
      const int s = row * 64 + p;
      af[mi] = *(const bf16x8*)&q_s[hbase + (size_t)s * 64 + ks * 32 + (l >> 4) * 8];
    }
#pragma unroll
    for (int ni = 0; ni < 4; ni++) {
      const int col = ni * 16 + (l & 15);
      const float* tp = &table[(size_t)(p - col + 63) * 64 + ks * 32 + (l >> 4) * 8];
      f32x4 t0 = *(const f32x4*)tp;
      f32x4 t1 = *(const f32x4*)(tp + 4);
      bf16x8 bb;
#pragma unroll
      for (int j = 0; j < 4; j++) { bb[j] = (bf16)t0[j]; bb[j + 4] = (bf16)t1[j]; }
      bfr[ni] = bb;
    }
#pragma unroll
    for (int mi = 0; mi < 4; mi++)
#pragma unroll
      for (int ni = 0; ni < 4; ni++)
        acc[mi][ni] = mfma16(af[mi], bfr[ni], acc[mi][ni]);
  }
#pragma unroll
  for (int mi = 0; mi < 4; mi++)
#pragma unroll
    for (int ni = 0; ni < 4; ni++)
#pragma unroll
      for (int i = 0; i < 4; i++) {
        const int row = mi * 16 + (l >> 4) * 4 + i;
        const int col = ni * 16 + (l & 15);
        const int sq = row * 64 + p;
        out[hbase + (size_t)sq * 64 + col] = acc[mi][ni][i];
      }
}

// ---------------- flash attention, 32x32 MFMA, key-split waves ----------------
// Block (qh, head): 64 queries, 4 waves. Wave w: query group qg=w&1 (32 q),
// key half kh2=w>>1 (32 keys of each 64-key tile). QK^T swapped (A=K, B=Q):
// lane owns query col r5=l&31; its 16 C-regs are keys (reg&3)+8*(reg>>2)+4h
// (h=l>>5). Per-wave online softmax; end-merge of (m,l,O) across key halves.
__global__ __launch_bounds__(256) void flash_attn(
    const bf16* __restrict__ q_s, const bf16* __restrict__ k_s,
    const bf16* __restrict__ v_t, const float* __restrict__ rph,
    const float* __restrict__ bias_w, bf16* __restrict__ attn_out) {
  __shared__ __align__(16) char smem[49408];
  bf16* lKb = (bf16*)smem;               // [2][64][64] K tile, swizzled
  bf16* lVb = (bf16*)(smem + 16384);     // [2][64][64] V^T tile, swizzled
  float* lBH = (float*)(smem + 32768);   // [64][65] rel_h bias

  const int tid = threadIdx.x;
  const int w = tid >> 6, l = tid & 63;
  const int r5 = l & 31, h = l >> 5, r7 = l & 7;
  const int qg = w & 1, kh2 = w >> 1;
  const int qh = blockIdx.x, head = blockIdx.y;
  const size_t hbase = (size_t)head << 18;
  const int qloc = qg * 32 + r5;
  const size_t sq = (size_t)qh * 64 + qloc;

  // ---- staging pointers (tile 0), incremented per tile ----
  const int ch0 = w * 2, ch1 = ch0 + 1;
  const int lr3 = l >> 3;
  const int swz = ((l & 7) ^ lr3) * 8;  // pre-swizzled source element offset
  const bf16* kp0 = k_s + hbase + (size_t)(ch0 * 8 + lr3) * 64 + swz;
  const bf16* kp1 = k_s + hbase + (size_t)(ch1 * 8 + lr3) * 64 + swz;
  const bf16* vp0 = v_t + hbase + (size_t)(ch0 * 8 + lr3) * 4096 + swz;
  const bf16* vp1 = v_t + hbase + (size_t)(ch1 * 8 + lr3) * 4096 + swz;

#define STAGE(buf)                                                        \
  do {                                                                    \
    gl_lds16(kp0, smem + (buf) * 8192 + ch0 * 1024);                      \
    gl_lds16(kp1, smem + (buf) * 8192 + ch1 * 1024);                      \
    gl_lds16(vp0, smem + 16384 + (buf) * 8192 + ch0 * 1024);              \
    gl_lds16(vp1, smem + 16384 + (buf) * 8192 + ch1 * 1024);              \
  } while (0)

  STAGE(0);
  kp0 += 4096; kp1 += 4096; vp0 += 64; vp1 += 64;

  // ---- prologue: fused rel_h -> lBH[q][kh]  (16x16 MFMA, wave = 16 queries) ----
  {
    const int q16 = l & 15, g4 = l >> 4;
    const size_t sq16 = (size_t)qh * 64 + w * 16 + q16;
    bf16x8 qf16[2];
    qf16[0] = *(const bf16x8*)&q_s[hbase + sq16 * 64 + g4 * 8];
    qf16[1] = *(const bf16x8*)&q_s[hbase + sq16 * 64 + 32 + g4 * 8];
    f32x4 abh[4] = {};
#pragma unroll
    for (int ks = 0; ks < 2; ks++)
#pragma unroll
      for (int ni = 0; ni < 4; ni++) {
        const int kh = ni * 16 + q16;
        const float* tp = &rph[(size_t)(qh + 63 - kh) * 64 + ks * 32 + g4 * 8];
        f32x4 t0 = *(const f32x4*)tp;
        f32x4 t1 = *(const f32x4*)(tp + 4);
        bf16x8 rf;
#pragma unroll
        for (int j = 0; j < 4; j++) { rf[j] = (bf16)t0[j]; rf[j + 4] = (bf16)t1[j]; }
        abh[ni] = mfma16(rf, qf16[ks], abh[ni]);
      }
#pragma unroll
    for (int ni = 0; ni < 4; ni++)
#pragma unroll
      for (int i = 0; i < 4; i++)
        lBH[(w * 16 + q16) * 65 + ni * 16 + g4 * 4 + i] = abh[ni][i];
  }

  // ---- main-loop Q fragments (32x32 B-operand layout) ----
  bf16x8 qv[4];
#pragma unroll
  for (int s = 0; s < 4; s++)
    qv[s] = *(const bf16x8*)&q_s[hbase + sq * 64 + s * 16 + h * 8];

  // rel_w bias in exp2 domain, per-lane C-reg order
  float c2[16];
#pragma unroll
  for (int G = 0; G < 4; G++) {
    f32x4 cv = *(const f32x4*)&bias_w[hbase + sq * 64 + kh2 * 32 + G * 8 + h * 4];
#pragma unroll
    for (int i = 0; i < 4; i++) c2[G * 4 + i] = cv[i] * L2E;
  }

  // LDS read offsets (bytes), loop-invariant
  int offK[4], offV[2][2];
  const int rowK = kh2 * 32 + r5;
#pragma unroll
  for (int s = 0; s < 4; s++)
    offK[s] = rowK * 128 + (((s * 2 + h) ^ r7) * 16);
#pragma unroll
  for (int T = 0; T < 2; T++)
#pragma unroll
    for (int st = 0; st < 2; st++)
      offV[T][st] = (T * 32 + r5) * 128 + (((kh2 * 4 + st * 2 + h) ^ r7) * 16);

  f32x16 o[2] = {};
  float mrun = -1e30f, lrun = 0.f;
  const float SC2 = 0.125f * L2E;

  __syncthreads();

  int cur = 0;
  for (int t = 0; t < 64; t++) {
    if (t < 63) {
      STAGE(cur ^ 1);
      kp0 += 4096; kp1 += 4096; vp0 += 64; vp1 += 64;
    }

    // ---- QK^T: one 32x32 tile, 4 K-steps ----
    const char* kb = smem + cur * 8192;
    f32x16 sacc = {0.f, 0.f, 0.f, 0.f, 0.f, 0.f, 0.f, 0.f,
                   0.f, 0.f, 0.f, 0.f, 0.f, 0.f, 0.f, 0.f};
#pragma unroll
    for (int s = 0; s < 4; s++) {
      bf16x8 kf = *(const bf16x8*)(kb + offK[s]);
      sacc = mfma32(kf, qv[s], sacc);
    }

    // ---- softmax over this wave's 32 keys (lane pair l, l+32) ----
    float p[16], pm = -1e30f;
#pragma unroll
    for (int j = 0; j < 16; j++) {
      p[j] = sacc[j] * SC2 + c2[j];
      pm = fmaxf(pm, p[j]);
    }
    pm = fmaxf(pm, __shfl_xor(pm, 32, 64));
    const float bh2 = lBH[qloc * 65 + t] * L2E;
    const float rmf = pm + bh2;

    if (!__all(rmf - mrun <= 8.f)) {
      const float mn = fmaxf(mrun, rmf);
      const float al = __builtin_amdgcn_exp2f(mrun - mn);
      mrun = mn;
      lrun *= al;
      o[0] *= al;
      o[1] *= al;
    }

    const float d = bh2 - mrun;
    float rs = 0.f;
    u32 w8[8];
#pragma unroll
    for (int j = 0; j < 8; j++) {
      float e0 = __builtin_amdgcn_exp2f(p[2 * j] + d);
      float e1 = __builtin_amdgcn_exp2f(p[2 * j + 1] + d);
      rs += e0 + e1;
      union { bf16 b[2]; u32 u; } cvu;
      cvu.b[0] = (bf16)e0;
      cvu.b[1] = (bf16)e1;
      w8[j] = cvu.u;
    }
    rs += __shfl_xor(rs, 32, 64);
    lrun += rs;

    // ---- PV: B-fragment assembly (lane<->lane+32 word exchange) + 4 MFMA ----
    const char* vb = smem + 16384 + cur * 8192;
#pragma unroll
    for (int st = 0; st < 2; st++) {
      u32 x0 = h ? w8[4 * st] : w8[4 * st + 2];
      u32 x1 = h ? w8[4 * st + 1] : w8[4 * st + 3];
      u32 p0 = (u32)__shfl_xor((int)x0, 32, 64);
      u32 p1 = (u32)__shfl_xor((int)x1, 32, 64);
      union { u32 u[4]; bf16x8 v; } pf;
      pf.u[0] = h ? p0 : w8[4 * st];
      pf.u[1] = h ? p1 : w8[4 * st + 1];
      pf.u[2] = h ? w8[4 * st + 2] : p0;
      pf.u[3] = h ? w8[4 * st + 3] : p1;
#pragma unroll
      for (int T = 0; T < 2; T++) {
        bf16x8 vf = *(const bf16x8*)(vb + offV[T][st]);
        o[T] = mfma32(vf, pf.v, o[T]);
      }
    }

    __syncthreads();
    cur ^= 1;
  }
#undef STAGE

  // ---- merge key halves: waves 2,3 publish; waves 0,1 combine + store ----
  float* MM = (float*)smem;          // m [2][32]
  float* ML = (float*)(smem + 256);  // l [2][32]
  float* MO = (float*)(smem + 512);  // O [2][32][64]
  if (w >= 2) {
    if (h == 0) { MM[qg * 32 + r5] = mrun; ML[qg * 32 + r5] = lrun; }
#pragma unroll
    for (int T = 0; T < 2; T++)
#pragma unroll
      for (int G = 0; G < 4; G++) {
        f32x4 ov;
#pragma unroll
        for (int i = 0; i < 4; i++) ov[i] = o[T][4 * G + i];
        *(f32x4*)&MO[qg * 2048 + r5 * 64 + T * 32 + G * 8 + h * 4] = ov;
      }
  }
  __syncthreads();
  if (w < 2) {
    const float mp = MM[qg * 32 + r5], lp = ML[qg * 32 + r5];
    const float mT = fmaxf(mrun, mp);
    const float a = __builtin_amdgcn_exp2f(mrun - mT);
    const float b = __builtin_amdgcn_exp2f(mp - mT);
    const float inv = 1.f / (lrun * a + lp * b);
#pragma unroll
    for (int T = 0; T < 2; T++)
#pragma unroll
      for (int G = 0; G < 4; G++) {
        f32x4 po = *(const f32x4*)&MO[qg * 2048 + r5 * 64 + T * 32 + G * 8 + h * 4];
        bf16x4 ob;
#pragma unroll
        for (int i = 0; i < 4; i++)
          ob[i] = (bf16)((o[T][4 * G + i] * a + po[i] * b) * inv);
        *(bf16x4*)&attn_out[sq * 768 + head * 64 + T * 32 + G * 8 + h * 4] = ob;
      }
  }
}

// ---------------- launch ----------------
extern "C" void kernel_launch(void* const* d_in, const int* in_sizes, int n_in,
                              void* d_out, int out_size, void* d_ws, size_t ws_size,
                              hipStream_t stream) {
  const float* x      = (const float*)d_in[0];
  const float* qkv_w  = (const float*)d_in[1];
  const float* qkv_b  = (const float*)d_in[2];
  const float* proj_w = (const float*)d_in[3];
  const float* proj_b = (const float*)d_in[4];
  const float* rph    = (const float*)d_in[5];
  const float* rpw    = (const float*)d_in[6];

  char* ws = (char*)d_ws;
  bf16*  xb    = (bf16*)(ws);                 //  6.29 MB [4096][768]
  bf16*  wqkv  = (bf16*)(ws + 6291456);       //  3.54 MB [2304][768]
  bf16*  wproj = (bf16*)(ws + 9830400);       //  1.18 MB [768][768]
  bf16*  q_s   = (bf16*)(ws + 11010048);      //  6.29 MB [12][4096][64]
  bf16*  k_s   = (bf16*)(ws + 17301504);      //  6.29 MB [12][4096][64]
  bf16*  v_t   = (bf16*)(ws + 23592960);      //  6.29 MB [12][64][4096]
  bf16*  attno = (bf16*)(ws + 29884416);      //  6.29 MB [4096][768]
  float* bwv   = (float*)(ws + 36175872);     // 12.58 MB [12][4096][64]

  cvt3<<<2688, 256, 0, stream>>>(x, xb, qkv_w, wqkv, proj_w, wproj);

  gemm128<0><<<dim3(18, 32), 256, 0, stream>>>(xb, wqkv, qkv_b, 768, 2304,
                                               q_s, k_s, v_t, nullptr);

  rel_pos_w<<<dim3(64, 12), 64, 0, stream>>>(q_s, rpw, bwv);

  flash_attn<<<dim3(64, 12), 256, 0, stream>>>(q_s, k_s, v_t, rph, bwv, attno);

  gemm128<1><<<dim3(6, 32), 256, 0, stream>>>(attno, wproj, proj_b, 768, 768,
                                              nullptr, nullptr, nullptr,
                                              (float*)d_out);
}

// Round 5
// 253.482 us; speedup vs baseline: 1.2085x; 1.2085x over previous
//
#include <hip/hip_runtime.h>

// SAM ViT-B global attention, MI355X bf16-MFMA implementation.
// R5: flash with XCD-pinned head->L2 residency, counted-vmcnt (never 0)
//     double-buffer pipeline with raw s_barriers, setprio around MFMA,
//     merge-race fix; gemm<0> V^T epilogue via LDS-bounce coalesced stores.

typedef __bf16 bf16;
typedef __bf16 bf16x8 __attribute__((ext_vector_type(8)));
typedef __bf16 bf16x4 __attribute__((ext_vector_type(4)));
typedef float f32x4 __attribute__((ext_vector_type(4)));
typedef float f32x16 __attribute__((ext_vector_type(16)));
typedef unsigned int u32;

__device__ __forceinline__ f32x4 mfma16(bf16x8 a, bf16x8 b, f32x4 c) {
  return __builtin_amdgcn_mfma_f32_16x16x32_bf16(a, b, c, 0, 0, 0);
}
__device__ __forceinline__ f32x16 mfma32(bf16x8 a, bf16x8 b, f32x16 c) {
  return __builtin_amdgcn_mfma_f32_32x32x16_bf16(a, b, c, 0, 0, 0);
}

typedef const __attribute__((address_space(1))) void* gas_ptr;
typedef __attribute__((address_space(3))) void* las_ptr;
__device__ __forceinline__ void gl_lds16(const void* g, void* l) {
  __builtin_amdgcn_global_load_lds((gas_ptr)g, (las_ptr)l, 16, 0, 0);
}

#define L2E 1.4426950408889634f

// ---------------- fp32 -> bf16 convert, 3 tensors in one launch ----------------
__global__ __launch_bounds__(256) void cvt3(
    const float* __restrict__ a, bf16* __restrict__ oa,
    const float* __restrict__ b, bf16* __restrict__ ob,
    const float* __restrict__ c, bf16* __restrict__ oc) {
  int blk = blockIdx.x;
  const float* src;
  bf16* dst;
  int base;
  if (blk < 1536)       { src = a; dst = oa; base = blk; }
  else if (blk < 2400)  { src = b; dst = ob; base = blk - 1536; }
  else                  { src = c; dst = oc; base = blk - 2400; }
  int idx = (base * 256 + threadIdx.x) * 8;
  f32x4 x = *(const f32x4*)&src[idx];
  f32x4 y = *(const f32x4*)&src[idx + 4];
  bf16x8 o;
#pragma unroll
  for (int j = 0; j < 4; j++) { o[j] = (bf16)x[j]; o[j + 4] = (bf16)y[j]; }
  *(bf16x8*)&dst[idx] = o;
}

// ---------------- 128x128 GEMM, C = A @ B^T + bias ----------------
// MODE 0: qkv epilogue -> q_s/k_s row-major scatter; V blocks (n0>=1536)
//         transposed via LDS bounce -> coalesced 16B stores into v_t.
// MODE 1: fp32 out [M][N].
template <int MODE>
__global__ __launch_bounds__(256) void gemm128(
    const bf16* __restrict__ A, const bf16* __restrict__ B,
    const float* __restrict__ bias, int K, int N,
    bf16* __restrict__ q_s, bf16* __restrict__ k_s, bf16* __restrict__ v_t,
    float* __restrict__ outf) {
  __shared__ __align__(16) bf16 lbuf[2][128 * 32];
  bf16* lA = lbuf[0];
  bf16* lB = lbuf[1];
  const int tid = threadIdx.x;
  const int w = tid >> 6, l = tid & 63;
  const int n0 = blockIdx.x * 128, m0 = blockIdx.y * 128;

  f32x4 acc[4][4] = {};

  const int ch0 = w * 2, ch1 = ch0 + 1;
  const int r0 = ch0 * 16 + (l >> 2), r1 = ch1 * 16 + (l >> 2);
  const int ce = (l & 3) * 8;
  const int mw = (w & 1) * 64, nw = (w >> 1) * 64;

  for (int k0 = 0; k0 < K; k0 += 32) {
    __syncthreads();
    gl_lds16(&A[(size_t)(m0 + r0) * K + k0 + ce], &lA[ch0 * 512]);
    gl_lds16(&A[(size_t)(m0 + r1) * K + k0 + ce], &lA[ch1 * 512]);
    gl_lds16(&B[(size_t)(n0 + r0) * K + k0 + ce], &lB[ch0 * 512]);
    gl_lds16(&B[(size_t)(n0 + r1) * K + k0 + ce], &lB[ch1 * 512]);
    __syncthreads();
    bf16x8 af[4], bfr[4];
#pragma unroll
    for (int i = 0; i < 4; i++)
      af[i] = *(const bf16x8*)&lA[(mw + i * 16 + (l & 15)) * 32 + (l >> 4) * 8];
#pragma unroll
    for (int i = 0; i < 4; i++)
      bfr[i] = *(const bf16x8*)&lB[(nw + i * 16 + (l & 15)) * 32 + (l >> 4) * 8];
#pragma unroll
    for (int mi = 0; mi < 4; mi++)
#pragma unroll
      for (int ni = 0; ni < 4; ni++)
        acc[mi][ni] = mfma16(af[mi], bfr[ni], acc[mi][ni]);
  }

  if (MODE == 0 && n0 >= 1536) {
    // ---- V block: transpose via LDS, coalesced stores into v_t[hd][m] ----
    bf16* Lt = &lbuf[0][0];  // 16KB contiguous
#pragma unroll 1
    for (int pass = 0; pass < 2; ++pass) {
      __syncthreads();
      if ((w >> 1) == pass) {
        char* R = (char*)Lt + (w & 1) * 8192;
#pragma unroll
        for (int ni = 0; ni < 4; ni++) {
          const float bv = bias[n0 + nw + ni * 16 + (l & 15)];
          const int nl = ni * 16 + (l & 15);
#pragma unroll
          for (int mi = 0; mi < 4; mi++)
#pragma unroll
            for (int i2 = 0; i2 < 2; i2++) {
              const int ml2 = (mi * 16 + (l >> 4) * 4 + i2 * 2) * 2;  // byte col
              union { bf16 b[2]; u32 u; } pk;
              pk.b[0] = (bf16)(acc[mi][ni][i2 * 2] + bv);
              pk.b[1] = (bf16)(acc[mi][ni][i2 * 2 + 1] + bv);
              *(u32*)(R + nl * 128 + (ml2 ^ ((nl & 7) << 4))) = pk.u;
            }
        }
      }
      __syncthreads();
      if ((w >> 1) == pass) {
        const char* R = (const char*)Lt + (w & 1) * 8192;
#pragma unroll
        for (int r = 0; r < 8; r++) {
          const int nl = r * 8 + (l >> 3);
          const int pc = ((l & 7) * 16) ^ ((nl & 7) << 4);
          bf16x8 val = *(const bf16x8*)(R + nl * 128 + pc);
          const int n = n0 + pass * 64 + nl;
          const int head = (n - 1536) >> 6, hd = n & 63;
          *(bf16x8*)&v_t[((size_t)(head * 64 + hd)) * 4096 + m0 + (w & 1) * 64 +
                         (l & 7) * 8] = val;
        }
      }
    }
    return;
  }

#pragma unroll
  for (int ni = 0; ni < 4; ni++) {
    const int n = n0 + nw + ni * 16 + (l & 15);
    const float bv = bias[n];
#pragma unroll
    for (int mi = 0; mi < 4; mi++) {
#pragma unroll
      for (int i = 0; i < 4; i++) {
        const int m = m0 + mw + mi * 16 + (l >> 4) * 4 + i;
        const float v = acc[mi][ni][i] + bv;
        if (MODE == 0) {
          const int which = n / 768, hn = n % 768;
          const int head = hn >> 6, hd = hn & 63;
          if (which == 0)      q_s[((size_t)head * 4096 + m) * 64 + hd] = (bf16)v;
          else                 k_s[((size_t)head * 4096 + m) * 64 + hd] = (bf16)v;
        } else {
          outf[(size_t)m * N + n] = v;
        }
      }
    }
  }
}

// ---------------- rel_w bias kernel ----------------
__global__ __launch_bounds__(64) void rel_pos_w(
    const bf16* __restrict__ q_s, const float* __restrict__ table,
    float* __restrict__ out) {
  const int l = threadIdx.x;
  const int p = blockIdx.x, head = blockIdx.y;
  const size_t hbase = (size_t)head * 4096 * 64;

  f32x4 acc[4][4] = {};
#pragma unroll
  for (int ks = 0; ks < 2; ks++) {
    bf16x8 af[4], bfr[4];
#pragma unroll
    for (int mi = 0; mi < 4; mi++) {
      const int row = mi * 16 + (l & 15);
      const int s = row * 64 + p;
      af[mi] = *(const bf16x8*)&q_s[hbase + (size_t)s * 64 + ks * 32 + (l >> 4) * 8];
    }
#pragma unroll
    for (int ni = 0; ni < 4; ni++) {
      const int col = ni * 16 + (l & 15);
      const float* tp = &table[(size_t)(p - col + 63) * 64 + ks * 32 + (l >> 4) * 8];
      f32x4 t0 = *(const f32x4*)tp;
      f32x4 t1 = *(const f32x4*)(tp + 4);
      bf16x8 bb;
#pragma unroll
      for (int j = 0; j < 4; j++) { bb[j] = (bf16)t0[j]; bb[j + 4] = (bf16)t1[j]; }
      bfr[ni] = bb;
    }
#pragma unroll
    for (int mi = 0; mi < 4; mi++)
#pragma unroll
      for (int ni = 0; ni < 4; ni++)
        acc[mi][ni] = mfma16(af[mi], bfr[ni], acc[mi][ni]);
  }
#pragma unroll
  for (int mi = 0; mi < 4; mi++)
#pragma unroll
    for (int ni = 0; ni < 4; ni++)
#pragma unroll
      for (int i = 0; i < 4; i++) {
        const int row = mi * 16 + (l >> 4) * 4 + i;
        const int col = ni * 16 + (l & 15);
        const int sq = row * 64 + p;
        out[hbase + (size_t)sq * 64 + col] = acc[mi][ni][i];
      }
}

// ---------------- flash attention, 32x32 MFMA, key-split waves ----------------
// Grid: 768 linear blocks, XCD-pinned: xcd=f&7, g=xcd*96+(f>>3),
// head=g>>6, qh=g&63 -> each XCD sees <=2 heads (2MB K/V, L2-resident).
// Pipeline: counted vmcnt(4) + raw barriers, loads 1 tile ahead, never drained.
__global__ __launch_bounds__(256) void flash_attn(
    const bf16* __restrict__ q_s, const bf16* __restrict__ k_s,
    const bf16* __restrict__ v_t, const float* __restrict__ rph,
    const float* __restrict__ bias_w, bf16* __restrict__ attn_out) {
  __shared__ __align__(16) char smem[49408];
  float* lBH = (float*)(smem + 32768);  // [64][65] rel_h bias

  const int tid = threadIdx.x;
  const int w = tid >> 6, l = tid & 63;
  const int r5 = l & 31, h = l >> 5, r7 = l & 7;
  const int qg = w & 1, kh2 = w >> 1;
  const int f = blockIdx.x;
  const int g = (f & 7) * 96 + (f >> 3);
  const int head = g >> 6, qh = g & 63;
  const size_t hbase = (size_t)head << 18;
  const int qloc = qg * 32 + r5;
  const size_t sq = (size_t)qh * 64 + qloc;

  // ---- staging pointers (tile 0), incremented per tile ----
  const int ch0 = w * 2, ch1 = ch0 + 1;
  const int lr3 = l >> 3;
  const int swz = ((l & 7) ^ lr3) * 8;  // pre-swizzled source element offset
  const bf16* kp0 = k_s + hbase + (size_t)(ch0 * 8 + lr3) * 64 + swz;
  const bf16* kp1 = k_s + hbase + (size_t)(ch1 * 8 + lr3) * 64 + swz;
  const bf16* vp0 = v_t + hbase + (size_t)(ch0 * 8 + lr3) * 4096 + swz;
  const bf16* vp1 = v_t + hbase + (size_t)(ch1 * 8 + lr3) * 4096 + swz;

#define STAGE(buf)                                                        \
  do {                                                                    \
    gl_lds16(kp0, smem + (buf) * 8192 + ch0 * 1024);                      \
    gl_lds16(kp1, smem + (buf) * 8192 + ch1 * 1024);                      \
    gl_lds16(vp0, smem + 16384 + (buf) * 8192 + ch0 * 1024);              \
    gl_lds16(vp1, smem + 16384 + (buf) * 8192 + ch1 * 1024);              \
  } while (0)

  STAGE(0);
  kp0 += 4096; kp1 += 4096; vp0 += 64; vp1 += 64;

  // ---- prologue: fused rel_h -> lBH[q][kh]  (16x16 MFMA, wave = 16 queries) ----
  {
    const int q16 = l & 15, g4 = l >> 4;
    const size_t sq16 = (size_t)qh * 64 + w * 16 + q16;
    bf16x8 qf16[2];
    qf16[0] = *(const bf16x8*)&q_s[hbase + sq16 * 64 + g4 * 8];
    qf16[1] = *(const bf16x8*)&q_s[hbase + sq16 * 64 + 32 + g4 * 8];
    f32x4 abh[4] = {};
#pragma unroll
    for (int ks = 0; ks < 2; ks++)
#pragma unroll
      for (int ni = 0; ni < 4; ni++) {
        const int kh = ni * 16 + q16;
        const float* tp = &rph[(size_t)(qh + 63 - kh) * 64 + ks * 32 + g4 * 8];
        f32x4 t0 = *(const f32x4*)tp;
        f32x4 t1 = *(const f32x4*)(tp + 4);
        bf16x8 rf;
#pragma unroll
        for (int j = 0; j < 4; j++) { rf[j] = (bf16)t0[j]; rf[j + 4] = (bf16)t1[j]; }
        abh[ni] = mfma16(rf, qf16[ks], abh[ni]);
      }
#pragma unroll
    for (int ni = 0; ni < 4; ni++)
#pragma unroll
      for (int i = 0; i < 4; i++)
        lBH[(w * 16 + q16) * 65 + ni * 16 + g4 * 4 + i] = abh[ni][i];
  }

  // ---- main-loop Q fragments (32x32 B-operand layout) ----
  bf16x8 qv[4];
#pragma unroll
  for (int s = 0; s < 4; s++)
    qv[s] = *(const bf16x8*)&q_s[hbase + sq * 64 + s * 16 + h * 8];

  // rel_w bias in exp2 domain, per-lane C-reg order
  float c2[16];
#pragma unroll
  for (int G = 0; G < 4; G++) {
    f32x4 cv = *(const f32x4*)&bias_w[hbase + sq * 64 + kh2 * 32 + G * 8 + h * 4];
#pragma unroll
    for (int i = 0; i < 4; i++) c2[G * 4 + i] = cv[i] * L2E;
  }

  // LDS read offsets (bytes), loop-invariant
  int offK[4], offV[2][2];
  const int rowK = kh2 * 32 + r5;
#pragma unroll
  for (int s = 0; s < 4; s++)
    offK[s] = rowK * 128 + (((s * 2 + h) ^ r7) * 16);
#pragma unroll
  for (int T = 0; T < 2; T++)
#pragma unroll
    for (int st = 0; st < 2; st++)
      offV[T][st] = (T * 32 + r5) * 128 + (((kh2 * 4 + st * 2 + h) ^ r7) * 16);

  f32x16 o[2] = {};
  float mrun = -1e30f, lrun = 0.f;
  const float SC2 = 0.125f * L2E;

  auto compute = [&](int t) {
    const char* kb = smem + (t & 1) * 8192;
    const char* vb = smem + 16384 + (t & 1) * 8192;

    // ---- QK^T: one 32x32 tile, 4 K-steps ----
    f32x16 sacc = {0.f, 0.f, 0.f, 0.f, 0.f, 0.f, 0.f, 0.f,
                   0.f, 0.f, 0.f, 0.f, 0.f, 0.f, 0.f, 0.f};
    __builtin_amdgcn_s_setprio(1);
#pragma unroll
    for (int s = 0; s < 4; s++) {
      bf16x8 kf = *(const bf16x8*)(kb + offK[s]);
      sacc = mfma32(kf, qv[s], sacc);
    }
    __builtin_amdgcn_s_setprio(0);

    // ---- softmax over this wave's 32 keys (lane pair l, l+32) ----
    float p[16], pm = -1e30f;
#pragma unroll
    for (int j = 0; j < 16; j++) {
      p[j] = sacc[j] * SC2 + c2[j];
      pm = fmaxf(pm, p[j]);
    }
    pm = fmaxf(pm, __shfl_xor(pm, 32, 64));
    const float bh2 = lBH[qloc * 65 + t] * L2E;
    const float rmf = pm + bh2;

    if (!__all(rmf - mrun <= 8.f)) {
      const float mn = fmaxf(mrun, rmf);
      const float al = __builtin_amdgcn_exp2f(mrun - mn);
      mrun = mn;
      lrun *= al;
      o[0] *= al;
      o[1] *= al;
    }

    const float d = bh2 - mrun;
    float rs = 0.f;
    u32 w8[8];
#pragma unroll
    for (int j = 0; j < 8; j++) {
      float e0 = __builtin_amdgcn_exp2f(p[2 * j] + d);
      float e1 = __builtin_amdgcn_exp2f(p[2 * j + 1] + d);
      rs += e0 + e1;
      union { bf16 b[2]; u32 u; } cvu;
      cvu.b[0] = (bf16)e0;
      cvu.b[1] = (bf16)e1;
      w8[j] = cvu.u;
    }
    rs += __shfl_xor(rs, 32, 64);
    lrun += rs;

    // ---- PV: B-fragment assembly (lane<->lane+32 word exchange) + 4 MFMA ----
#pragma unroll
    for (int st = 0; st < 2; st++) {
      u32 x0 = h ? w8[4 * st] : w8[4 * st + 2];
      u32 x1 = h ? w8[4 * st + 1] : w8[4 * st + 3];
      u32 p0 = (u32)__shfl_xor((int)x0, 32, 64);
      u32 p1 = (u32)__shfl_xor((int)x1, 32, 64);
      union { u32 u[4]; bf16x8 v; } pf;
      pf.u[0] = h ? p0 : w8[4 * st];
      pf.u[1] = h ? p1 : w8[4 * st + 1];
      pf.u[2] = h ? w8[4 * st + 2] : p0;
      pf.u[3] = h ? w8[4 * st + 3] : p1;
      __builtin_amdgcn_s_setprio(1);
#pragma unroll
      for (int T = 0; T < 2; T++) {
        bf16x8 vf = *(const bf16x8*)(vb + offV[T][st]);
        o[T] = mfma32(vf, pf.v, o[T]);
      }
      __builtin_amdgcn_s_setprio(0);
    }
  };

  __syncthreads();  // lBH ready; S(0) drained (compiler vmcnt(0) at barrier)

  for (int t = 0; t < 63; t++) {
    STAGE((t + 1) & 1);  // safe: buf was last read at iter t-1, end-barrier'd
    kp0 += 4096; kp1 += 4096; vp0 += 64; vp1 += 64;
    asm volatile("s_waitcnt vmcnt(4)" ::: "memory");  // S(t) landed (own)
    __builtin_amdgcn_s_barrier();                     // all waves' S(t) landed
    __builtin_amdgcn_sched_barrier(0);
    compute(t);
    __builtin_amdgcn_s_barrier();                     // reads of buf t&1 done
    __builtin_amdgcn_sched_barrier(0);
  }
  asm volatile("s_waitcnt vmcnt(0)" ::: "memory");
  __builtin_amdgcn_s_barrier();
  __builtin_amdgcn_sched_barrier(0);
  compute(63);
  __syncthreads();  // merge-race fix: all compute done before LDS reuse

  // ---- merge key halves: waves 2,3 publish; waves 0,1 combine + store ----
  float* MM = (float*)smem;          // m [2][32]
  float* ML = (float*)(smem + 256);  // l [2][32]
  float* MO = (float*)(smem + 512);  // O [2][32][64]
  if (w >= 2) {
    if (h == 0) { MM[qg * 32 + r5] = mrun; ML[qg * 32 + r5] = lrun; }
#pragma unroll
    for (int T = 0; T < 2; T++)
#pragma unroll
      for (int G = 0; G < 4; G++) {
        f32x4 ov;
#pragma unroll
        for (int i = 0; i < 4; i++) ov[i] = o[T][4 * G + i];
        *(f32x4*)&MO[qg * 2048 + r5 * 64 + T * 32 + G * 8 + h * 4] = ov;
      }
  }
  __syncthreads();
  if (w < 2) {
    const float mp = MM[qg * 32 + r5], lp = ML[qg * 32 + r5];
    const float mT = fmaxf(mrun, mp);
    const float a = __builtin_amdgcn_exp2f(mrun - mT);
    const float b = __builtin_amdgcn_exp2f(mp - mT);
    const float inv = 1.f / (lrun * a + lp * b);
#pragma unroll
    for (int T = 0; T < 2; T++)
#pragma unroll
      for (int G = 0; G < 4; G++) {
        f32x4 po = *(const f32x4*)&MO[qg * 2048 + r5 * 64 + T * 32 + G * 8 + h * 4];
        bf16x4 ob;
#pragma unroll
        for (int i = 0; i < 4; i++)
          ob[i] = (bf16)((o[T][4 * G + i] * a + po[i] * b) * inv);
        *(bf16x4*)&attn_out[sq * 768 + head * 64 + T * 32 + G * 8 + h * 4] = ob;
      }
  }
#undef STAGE
}

// ---------------- launch ----------------
extern "C" void kernel_launch(void* const* d_in, const int* in_sizes, int n_in,
                              void* d_out, int out_size, void* d_ws, size_t ws_size,
                              hipStream_t stream) {
  const float* x      = (const float*)d_in[0];
  const float* qkv_w  = (const float*)d_in[1];
  const float* qkv_b  = (const float*)d_in[2];
  const float* proj_w = (const float*)d_in[3];
  const float* proj_b = (const float*)d_in[4];
  const float* rph    = (const float*)d_in[5];
  const float* rpw    = (const float*)d_in[6];

  char* ws = (char*)d_ws;
  bf16*  xb    = (bf16*)(ws);                 //  6.29 MB [4096][768]
  bf16*  wqkv  = (bf16*)(ws + 6291456);       //  3.54 MB [2304][768]
  bf16*  wproj = (bf16*)(ws + 9830400);       //  1.18 MB [768][768]
  bf16*  q_s   = (bf16*)(ws + 11010048);      //  6.29 MB [12][4096][64]
  bf16*  k_s   = (bf16*)(ws + 17301504);      //  6.29 MB [12][4096][64]
  bf16*  v_t   = (bf16*)(ws + 23592960);      //  6.29 MB [12][64][4096]
  bf16*  attno = (bf16*)(ws + 29884416);      //  6.29 MB [4096][768]
  float* bwv   = (float*)(ws + 36175872);     // 12.58 MB [12][4096][64]

  cvt3<<<2688, 256, 0, stream>>>(x, xb, qkv_w, wqkv, proj_w, wproj);

  gemm128<0><<<dim3(18, 32), 256, 0, stream>>>(xb, wqkv, qkv_b, 768, 2304,
                                               q_s, k_s, v_t, nullptr);

  rel_pos_w<<<dim3(64, 12), 64, 0, stream>>>(q_s, rpw, bwv);

  flash_attn<<<768, 256, 0, stream>>>(q_s, k_s, v_t, rph, bwv, attno);

  gemm128<1><<<dim3(6, 32), 256, 0, stream>>>(attno, wproj, proj_b, 768, 768,
                                              nullptr, nullptr, nullptr,
                                              (float*)d_out);
}

// Round 6
// 241.656 us; speedup vs baseline: 1.2677x; 1.0489x over previous
//
#include <hip/hip_runtime.h>

// SAM ViT-B global attention, MI355X bf16-MFMA implementation.
// R6: bank-conflict-free LDS swizzle f(row)=(row^(row>>3))&7 everywhere
//     (stage-source + read side), permlane32_swap for all cross-half traffic
//     (off the DS pipe), GEMM BK=64 with swizzled fragment reads.

typedef __bf16 bf16;
typedef __bf16 bf16x8 __attribute__((ext_vector_type(8)));
typedef __bf16 bf16x4 __attribute__((ext_vector_type(4)));
typedef float f32x4 __attribute__((ext_vector_type(4)));
typedef float f32x16 __attribute__((ext_vector_type(16)));
typedef unsigned int u32;

__device__ __forceinline__ f32x4 mfma16(bf16x8 a, bf16x8 b, f32x4 c) {
  return __builtin_amdgcn_mfma_f32_16x16x32_bf16(a, b, c, 0, 0, 0);
}
__device__ __forceinline__ f32x16 mfma32(bf16x8 a, bf16x8 b, f32x16 c) {
  return __builtin_amdgcn_mfma_f32_32x32x16_bf16(a, b, c, 0, 0, 0);
}

typedef const __attribute__((address_space(1))) void* gas_ptr;
typedef __attribute__((address_space(3))) void* las_ptr;
__device__ __forceinline__ void gl_lds16(const void* g, void* l) {
  __builtin_amdgcn_global_load_lds((gas_ptr)g, (las_ptr)l, 16, 0, 0);
}

// ---- permlane32_swap: VALU half-swap (new_a = {a.lo,b.lo}, new_b = {a.hi,b.hi})
#if defined(__has_builtin)
#if __has_builtin(__builtin_amdgcn_permlane32_swap)
#define HAVE_PLSWAP 1
#endif
#endif
__device__ __forceinline__ void pswap_u(u32& a, u32& b) {
#ifdef HAVE_PLSWAP
  auto r = __builtin_amdgcn_permlane32_swap(a, b, false, false);
  a = r[0]; b = r[1];
#else
  const bool hi = (threadIdx.x & 32) != 0;
  u32 sa = (u32)__shfl_xor((int)a, 32, 64);
  u32 sb = (u32)__shfl_xor((int)b, 32, 64);
  u32 na = hi ? sb : a;
  u32 nb = hi ? b : sa;
  a = na; b = nb;
#endif
}
__device__ __forceinline__ void pswap_f(float& a, float& b) {
  u32 x = __float_as_uint(a), y = __float_as_uint(b);
  pswap_u(x, y);
  a = __uint_as_float(x); b = __uint_as_float(y);
}

#define L2E 1.4426950408889634f

// ---------------- fp32 -> bf16 convert, 3 tensors in one launch ----------------
__global__ __launch_bounds__(256) void cvt3(
    const float* __restrict__ a, bf16* __restrict__ oa,
    const float* __restrict__ b, bf16* __restrict__ ob,
    const float* __restrict__ c, bf16* __restrict__ oc) {
  int blk = blockIdx.x;
  const float* src;
  bf16* dst;
  int base;
  if (blk < 1536)       { src = a; dst = oa; base = blk; }
  else if (blk < 2400)  { src = b; dst = ob; base = blk - 1536; }
  else                  { src = c; dst = oc; base = blk - 2400; }
  int idx = (base * 256 + threadIdx.x) * 8;
  f32x4 x = *(const f32x4*)&src[idx];
  f32x4 y = *(const f32x4*)&src[idx + 4];
  bf16x8 o;
#pragma unroll
  for (int j = 0; j < 4; j++) { o[j] = (bf16)x[j]; o[j + 4] = (bf16)y[j]; }
  *(bf16x8*)&dst[idx] = o;
}

// ---------------- 128x128 GEMM, BK=64, C = A @ B^T + bias ----------------
// LDS rows 64 elems (128B); slot s of row r holds logical chunk s ^ f(r),
// f(r) = (r ^ (r>>3)) & 7  -> conflict-free ds_read_b128 everywhere.
template <int MODE>
__global__ __launch_bounds__(256) void gemm128(
    const bf16* __restrict__ A, const bf16* __restrict__ B,
    const float* __restrict__ bias, int K, int N,
    bf16* __restrict__ q_s, bf16* __restrict__ k_s, bf16* __restrict__ v_t,
    float* __restrict__ outf) {
  __shared__ __align__(16) bf16 lA[128 * 64];
  __shared__ __align__(16) bf16 lB[128 * 64];
  const int tid = threadIdx.x;
  const int w = tid >> 6, l = tid & 63;
  const int n0 = blockIdx.x * 128, m0 = blockIdx.y * 128;

  f32x4 acc[4][4] = {};

  // staging: 16 chunks of 1KB per matrix; wave w stages chunks 4w..4w+3.
  // chunk c: row = c*8 + (l>>3); lane fetches logical slot (l&7)^(l>>3)^(c&7).
  int rowc[4], sloc[4];
#pragma unroll
  for (int j = 0; j < 4; j++) {
    const int c = w * 4 + j;
    rowc[j] = c * 8 + (l >> 3);
    sloc[j] = (((l & 7) ^ (l >> 3) ^ c) & 7) * 8;
  }
  const int mw = (w & 1) * 64, nw = (w >> 1) * 64;

  for (int k0 = 0; k0 < K; k0 += 64) {
    __syncthreads();
#pragma unroll
    for (int j = 0; j < 4; j++) {
      gl_lds16(&A[(size_t)(m0 + rowc[j]) * K + k0 + sloc[j]],
               (char*)lA + (w * 4 + j) * 1024);
      gl_lds16(&B[(size_t)(n0 + rowc[j]) * K + k0 + sloc[j]],
               (char*)lB + (w * 4 + j) * 1024);
    }
    __syncthreads();
    bf16x8 af[2][4], bfr[2][4];
#pragma unroll
    for (int ks = 0; ks < 2; ks++)
#pragma unroll
      for (int i = 0; i < 4; i++) {
        const int rA = mw + i * 16 + (l & 15);
        const int rB = nw + i * 16 + (l & 15);
        const int slot = ks * 4 + (l >> 4);
        const int fA = ((rA ^ (rA >> 3)) & 7), fB = ((rB ^ (rB >> 3)) & 7);
        af[ks][i] = *(const bf16x8*)((const char*)lA + rA * 128 + ((slot ^ fA) & 7) * 16);
        bfr[ks][i] = *(const bf16x8*)((const char*)lB + rB * 128 + ((slot ^ fB) & 7) * 16);
      }
#pragma unroll
    for (int ks = 0; ks < 2; ks++)
#pragma unroll
      for (int mi = 0; mi < 4; mi++)
#pragma unroll
        for (int ni = 0; ni < 4; ni++)
          acc[mi][ni] = mfma16(af[ks][mi], bfr[ks][ni], acc[mi][ni]);
  }

  if (MODE == 0 && n0 >= 1536) {
    // ---- V block: transpose via LDS, coalesced stores into v_t[hd][m] ----
    bf16* Lt = lA;
#pragma unroll 1
    for (int pass = 0; pass < 2; ++pass) {
      __syncthreads();
      if ((w >> 1) == pass) {
        char* R = (char*)Lt + (w & 1) * 8192;
#pragma unroll
        for (int ni = 0; ni < 4; ni++) {
          const float bv = bias[n0 + nw + ni * 16 + (l & 15)];
          const int nl = ni * 16 + (l & 15);
#pragma unroll
          for (int mi = 0; mi < 4; mi++)
#pragma unroll
            for (int i2 = 0; i2 < 2; i2++) {
              const int ml2 = (mi * 16 + (l >> 4) * 4 + i2 * 2) * 2;  // byte col
              union { bf16 b[2]; u32 u; } pk;
              pk.b[0] = (bf16)(acc[mi][ni][i2 * 2] + bv);
              pk.b[1] = (bf16)(acc[mi][ni][i2 * 2 + 1] + bv);
              *(u32*)(R + nl * 128 + (ml2 ^ ((nl & 7) << 4))) = pk.u;
            }
        }
      }
      __syncthreads();
      if ((w >> 1) == pass) {
        const char* R = (const char*)Lt + (w & 1) * 8192;
#pragma unroll
        for (int r = 0; r < 8; r++) {
          const int nl = r * 8 + (l >> 3);
          const int pc = ((l & 7) * 16) ^ ((nl & 7) << 4);
          bf16x8 val = *(const bf16x8*)(R + nl * 128 + pc);
          const int n = n0 + pass * 64 + nl;
          const int head = (n - 1536) >> 6, hd = n & 63;
          *(bf16x8*)&v_t[((size_t)(head * 64 + hd)) * 4096 + m0 + (w & 1) * 64 +
                         (l & 7) * 8] = val;
        }
      }
    }
    return;
  }

#pragma unroll
  for (int ni = 0; ni < 4; ni++) {
    const int n = n0 + nw + ni * 16 + (l & 15);
    const float bv = bias[n];
#pragma unroll
    for (int mi = 0; mi < 4; mi++) {
#pragma unroll
      for (int i = 0; i < 4; i++) {
        const int m = m0 + mw + mi * 16 + (l >> 4) * 4 + i;
        const float v = acc[mi][ni][i] + bv;
        if (MODE == 0) {
          const int which = n / 768, hn = n % 768;
          const int head = hn >> 6, hd = hn & 63;
          if (which == 0)      q_s[((size_t)head * 4096 + m) * 64 + hd] = (bf16)v;
          else                 k_s[((size_t)head * 4096 + m) * 64 + hd] = (bf16)v;
        } else {
          outf[(size_t)m * N + n] = v;
        }
      }
    }
  }
}

// ---------------- rel_w bias kernel ----------------
__global__ __launch_bounds__(64) void rel_pos_w(
    const bf16* __restrict__ q_s, const float* __restrict__ table,
    float* __restrict__ out) {
  const int l = threadIdx.x;
  const int p = blockIdx.x, head = blockIdx.y;
  const size_t hbase = (size_t)head * 4096 * 64;

  f32x4 acc[4][4] = {};
#pragma unroll
  for (int ks = 0; ks < 2; ks++) {
    bf16x8 af[4], bfr[4];
#pragma unroll
    for (int mi = 0; mi < 4; mi++) {
      const int row = mi * 16 + (l & 15);
      const int s = row * 64 + p;
      af[mi] = *(const bf16x8*)&q_s[hbase + (size_t)s * 64 + ks * 32 + (l >> 4) * 8];
    }
#pragma unroll
    for (int ni = 0; ni < 4; ni++) {
      const int col = ni * 16 + (l & 15);
      const float* tp = &table[(size_t)(p - col + 63) * 64 + ks * 32 + (l >> 4) * 8];
      f32x4 t0 = *(const f32x4*)tp;
      f32x4 t1 = *(const f32x4*)(tp + 4);
      bf16x8 bb;
#pragma unroll
      for (int j = 0; j < 4; j++) { bb[j] = (bf16)t0[j]; bb[j + 4] = (bf16)t1[j]; }
      bfr[ni] = bb;
    }
#pragma unroll
    for (int mi = 0; mi < 4; mi++)
#pragma unroll
      for (int ni = 0; ni < 4; ni++)
        acc[mi][ni] = mfma16(af[mi], bfr[ni], acc[mi][ni]);
  }
#pragma unroll
  for (int mi = 0; mi < 4; mi++)
#pragma unroll
    for (int ni = 0; ni < 4; ni++)
#pragma unroll
      for (int i = 0; i < 4; i++) {
        const int row = mi * 16 + (l >> 4) * 4 + i;
        const int col = ni * 16 + (l & 15);
        const int sq = row * 64 + p;
        out[hbase + (size_t)sq * 64 + col] = acc[mi][ni][i];
      }
}

// ---------------- flash attention, 32x32 MFMA, key-split waves ----------------
// Grid: 768 linear blocks, XCD-pinned. Swizzle f(row)=(row^(row>>3))&7 on
// both stage-source and reads; permlane32_swap for all cross-half traffic.
__global__ __launch_bounds__(256) void flash_attn(
    const bf16* __restrict__ q_s, const bf16* __restrict__ k_s,
    const bf16* __restrict__ v_t, const float* __restrict__ rph,
    const float* __restrict__ bias_w, bf16* __restrict__ attn_out) {
  __shared__ __align__(16) char smem[49408];
  float* lBH = (float*)(smem + 32768);  // [64][65] rel_h bias

  const int tid = threadIdx.x;
  const int w = tid >> 6, l = tid & 63;
  const int r5 = l & 31, h = l >> 5;
  const int qg = w & 1, kh2 = w >> 1;
  const int f = blockIdx.x;
  const int g = (f & 7) * 96 + (f >> 3);
  const int head = g >> 6, qh = g & 63;
  const size_t hbase = (size_t)head << 18;
  const int qloc = qg * 32 + r5;
  const size_t sq = (size_t)qh * 64 + qloc;

  // ---- staging pointers (tile 0), incremented per tile ----
  const int ch0 = w * 2, ch1 = ch0 + 1;
  const int lr3 = l >> 3;
  const int swz0 = (((l & 7) ^ lr3 ^ ch0) & 7) * 8;
  const int swz1 = (((l & 7) ^ lr3 ^ ch1) & 7) * 8;
  const bf16* kp0 = k_s + hbase + (size_t)(ch0 * 8 + lr3) * 64 + swz0;
  const bf16* kp1 = k_s + hbase + (size_t)(ch1 * 8 + lr3) * 64 + swz1;
  const bf16* vp0 = v_t + hbase + (size_t)(ch0 * 8 + lr3) * 4096 + swz0;
  const bf16* vp1 = v_t + hbase + (size_t)(ch1 * 8 + lr3) * 4096 + swz1;

#define STAGE(buf)                                                        \
  do {                                                                    \
    gl_lds16(kp0, smem + (buf) * 8192 + ch0 * 1024);                      \
    gl_lds16(kp1, smem + (buf) * 8192 + ch1 * 1024);                      \
    gl_lds16(vp0, smem + 16384 + (buf) * 8192 + ch0 * 1024);              \
    gl_lds16(vp1, smem + 16384 + (buf) * 8192 + ch1 * 1024);              \
  } while (0)

  STAGE(0);
  kp0 += 4096; kp1 += 4096; vp0 += 64; vp1 += 64;

  // ---- prologue: fused rel_h -> lBH[q][kh]  (16x16 MFMA, wave = 16 queries) ----
  {
    const int q16 = l & 15, g4 = l >> 4;
    const size_t sq16 = (size_t)qh * 64 + w * 16 + q16;
    bf16x8 qf16[2];
    qf16[0] = *(const bf16x8*)&q_s[hbase + sq16 * 64 + g4 * 8];
    qf16[1] = *(const bf16x8*)&q_s[hbase + sq16 * 64 + 32 + g4 * 8];
    f32x4 abh[4] = {};
#pragma unroll
    for (int ks = 0; ks < 2; ks++)
#pragma unroll
      for (int ni = 0; ni < 4; ni++) {
        const int kh = ni * 16 + q16;
        const float* tp = &rph[(size_t)(qh + 63 - kh) * 64 + ks * 32 + g4 * 8];
        f32x4 t0 = *(const f32x4*)tp;
        f32x4 t1 = *(const f32x4*)(tp + 4);
        bf16x8 rf;
#pragma unroll
        for (int j = 0; j < 4; j++) { rf[j] = (bf16)t0[j]; rf[j + 4] = (bf16)t1[j]; }
        abh[ni] = mfma16(rf, qf16[ks], abh[ni]);
      }
#pragma unroll
    for (int ni = 0; ni < 4; ni++)
#pragma unroll
      for (int i = 0; i < 4; i++)
        lBH[(w * 16 + q16) * 65 + ni * 16 + g4 * 4 + i] = abh[ni][i];
  }

  // ---- main-loop Q fragments (32x32 B-operand layout) ----
  bf16x8 qv[4];
#pragma unroll
  for (int s = 0; s < 4; s++)
    qv[s] = *(const bf16x8*)&q_s[hbase + sq * 64 + s * 16 + h * 8];

  // rel_w bias in exp2 domain, per-lane C-reg order
  float c2[16];
#pragma unroll
  for (int G = 0; G < 4; G++) {
    f32x4 cv = *(const f32x4*)&bias_w[hbase + sq * 64 + kh2 * 32 + G * 8 + h * 4];
#pragma unroll
    for (int i = 0; i < 4; i++) c2[G * 4 + i] = cv[i] * L2E;
  }

  // LDS read offsets (bytes), loop-invariant; f(row)=(row^(row>>3))&7
  int offK[4], offV[2][2];
  const int rowK = kh2 * 32 + r5;
  const int fK = ((l & 7) ^ (kh2 * 4 + ((l >> 3) & 3))) & 7;
#pragma unroll
  for (int s = 0; s < 4; s++)
    offK[s] = rowK * 128 + (((s * 2 + h) ^ fK) & 7) * 16;
#pragma unroll
  for (int T = 0; T < 2; T++) {
    const int fV = ((l & 7) ^ (T * 4 + ((l >> 3) & 3))) & 7;
#pragma unroll
    for (int st = 0; st < 2; st++)
      offV[T][st] = (T * 32 + r5) * 128 + (((kh2 * 4 + st * 2 + h) ^ fV) & 7) * 16;
  }

  f32x16 o[2] = {};
  float mrun = -1e30f, lrun = 0.f;
  const float SC2 = 0.125f * L2E;

  auto compute = [&](int t) {
    const char* kb = smem + (t & 1) * 8192;
    const char* vb = smem + 16384 + (t & 1) * 8192;

    // ---- QK^T: one 32x32 tile, 4 K-steps ----
    f32x16 sacc = {0.f, 0.f, 0.f, 0.f, 0.f, 0.f, 0.f, 0.f,
                   0.f, 0.f, 0.f, 0.f, 0.f, 0.f, 0.f, 0.f};
    __builtin_amdgcn_s_setprio(1);
#pragma unroll
    for (int s = 0; s < 4; s++) {
      bf16x8 kf = *(const bf16x8*)(kb + offK[s]);
      sacc = mfma32(kf, qv[s], sacc);
    }
    __builtin_amdgcn_s_setprio(0);

    // ---- softmax over this wave's 32 keys (lane pair l, l+32) ----
    float p[16], pm = -1e30f;
#pragma unroll
    for (int j = 0; j < 16; j++) {
      p[j] = sacc[j] * SC2 + c2[j];
      pm = fmaxf(pm, p[j]);
    }
    { float t2 = pm; pswap_f(t2, pm); pm = fmaxf(t2, pm); }
    const float bh2 = lBH[qloc * 65 + t] * L2E;
    const float rmf = pm + bh2;

    if (!__all(rmf - mrun <= 8.f)) {
      const float mn = fmaxf(mrun, rmf);
      const float al = __builtin_amdgcn_exp2f(mrun - mn);
      mrun = mn;
      lrun *= al;
      o[0] *= al;
      o[1] *= al;
    }

    const float d = bh2 - mrun;
    float rs = 0.f;
    u32 w8[8];
#pragma unroll
    for (int j = 0; j < 8; j++) {
      float e0 = __builtin_amdgcn_exp2f(p[2 * j] + d);
      float e1 = __builtin_amdgcn_exp2f(p[2 * j + 1] + d);
      rs += e0 + e1;
      union { bf16 b[2]; u32 u; } cvu;
      cvu.b[0] = (bf16)e0;
      cvu.b[1] = (bf16)e1;
      w8[j] = cvu.u;
    }
    { float t2 = rs; pswap_f(t2, rs); rs = t2 + rs; }
    lrun += rs;

    // ---- PV: B-fragments via 2 permlane swaps per st + 4 MFMA ----
#pragma unroll
    for (int st = 0; st < 2; st++) {
      union { u32 u[4]; bf16x8 v; } pf;
      u32 a0 = w8[4 * st], b0 = w8[4 * st + 2];
      u32 a1 = w8[4 * st + 1], b1 = w8[4 * st + 3];
      pswap_u(a0, b0);  // a0={w0.lo,w2.lo}, b0={w0.hi,w2.hi}
      pswap_u(a1, b1);
      pf.u[0] = a0; pf.u[1] = a1; pf.u[2] = b0; pf.u[3] = b1;
      __builtin_amdgcn_s_setprio(1);
#pragma unroll
      for (int T = 0; T < 2; T++) {
        bf16x8 vf = *(const bf16x8*)(vb + offV[T][st]);
        o[T] = mfma32(vf, pf.v, o[T]);
      }
      __builtin_amdgcn_s_setprio(0);
    }
  };

  __syncthreads();  // lBH ready; S(0) drained (compiler vmcnt(0) at barrier)

  for (int t = 0; t < 63; t++) {
    STAGE((t + 1) & 1);
    kp0 += 4096; kp1 += 4096; vp0 += 64; vp1 += 64;
    asm volatile("s_waitcnt vmcnt(4)" ::: "memory");  // S(t) landed (own)
    __builtin_amdgcn_s_barrier();                     // all waves' S(t) landed
    __builtin_amdgcn_sched_barrier(0);
    compute(t);
    __builtin_amdgcn_s_barrier();                     // reads of buf t&1 done
    __builtin_amdgcn_sched_barrier(0);
  }
  asm volatile("s_waitcnt vmcnt(0)" ::: "memory");
  __builtin_amdgcn_s_barrier();
  __builtin_amdgcn_sched_barrier(0);
  compute(63);
  __syncthreads();  // all compute done before LDS reuse

  // ---- merge key halves: waves 2,3 publish; waves 0,1 combine + store ----
  float* MM = (float*)smem;          // m [2][32]
  float* ML = (float*)(smem + 256);  // l [2][32]
  float* MO = (float*)(smem + 512);  // O [2][32][64]
  if (w >= 2) {
    if (h == 0) { MM[qg * 32 + r5] = mrun; ML[qg * 32 + r5] = lrun; }
#pragma unroll
    for (int T = 0; T < 2; T++)
#pragma unroll
      for (int G = 0; G < 4; G++) {
        f32x4 ov;
#pragma unroll
        for (int i = 0; i < 4; i++) ov[i] = o[T][4 * G + i];
        *(f32x4*)&MO[qg * 2048 + r5 * 64 + T * 32 + G * 8 + h * 4] = ov;
      }
  }
  __syncthreads();
  if (w < 2) {
    const float mp = MM[qg * 32 + r5], lp = ML[qg * 32 + r5];
    const float mT = fmaxf(mrun, mp);
    const float a = __builtin_amdgcn_exp2f(mrun - mT);
    const float b = __builtin_amdgcn_exp2f(mp - mT);
    const float inv = 1.f / (lrun * a + lp * b);
#pragma unroll
    for (int T = 0; T < 2; T++)
#pragma unroll
      for (int G = 0; G < 4; G++) {
        f32x4 po = *(const f32x4*)&MO[qg * 2048 + r5 * 64 + T * 32 + G * 8 + h * 4];
        bf16x4 ob;
#pragma unroll
        for (int i = 0; i < 4; i++)
          ob[i] = (bf16)((o[T][4 * G + i] * a + po[i] * b) * inv);
        *(bf16x4*)&attn_out[sq * 768 + head * 64 + T * 32 + G * 8 + h * 4] = ob;
      }
  }
#undef STAGE
}

// ---------------- launch ----------------
extern "C" void kernel_launch(void* const* d_in, const int* in_sizes, int n_in,
                              void* d_out, int out_size, void* d_ws, size_t ws_size,
                              hipStream_t stream) {
  const float* x      = (const float*)d_in[0];
  const float* qkv_w  = (const float*)d_in[1];
  const float* qkv_b  = (const float*)d_in[2];
  const float* proj_w = (const float*)d_in[3];
  const float* proj_b = (const float*)d_in[4];
  const float* rph    = (const float*)d_in[5];
  const float* rpw    = (const float*)d_in[6];

  char* ws = (char*)d_ws;
  bf16*  xb    = (bf16*)(ws);                 //  6.29 MB [4096][768]
  bf16*  wqkv  = (bf16*)(ws + 6291456);       //  3.54 MB [2304][768]
  bf16*  wproj = (bf16*)(ws + 9830400);       //  1.18 MB [768][768]
  bf16*  q_s   = (bf16*)(ws + 11010048);      //  6.29 MB [12][4096][64]
  bf16*  k_s   = (bf16*)(ws + 17301504);      //  6.29 MB [12][4096][64]
  bf16*  v_t   = (bf16*)(ws + 23592960);      //  6.29 MB [12][64][4096]
  bf16*  attno = (bf16*)(ws + 29884416);      //  6.29 MB [4096][768]
  float* bwv   = (float*)(ws + 36175872);     // 12.58 MB [12][4096][64]

  cvt3<<<2688, 256, 0, stream>>>(x, xb, qkv_w, wqkv, proj_w, wproj);

  gemm128<0><<<dim3(18, 32), 256, 0, stream>>>(xb, wqkv, qkv_b, 768, 2304,
                                               q_s, k_s, v_t, nullptr);

  rel_pos_w<<<dim3(64, 12), 64, 0, stream>>>(q_s, rpw, bwv);

  flash_attn<<<768, 256, 0, stream>>>(q_s, k_s, v_t, rph, bwv, attno);

  gemm128<1><<<dim3(6, 32), 256, 0, stream>>>(attno, wproj, proj_b, 768, 768,
                                              nullptr, nullptr, nullptr,
                                              (float*)d_out);
}